// Round 10
// baseline (1562.594 us; speedup 1.0000x reference)
//
#include <hip/hip_runtime.h>

typedef unsigned short u16;
typedef __attribute__((ext_vector_type(8))) short short8;
typedef __attribute__((ext_vector_type(4))) float f32x4;

#define B_TOT 4096
#define T_STEPS 128
#define SMEM_BYTES 156800

__device__ __forceinline__ u16 f2bf(float x) {
  union { float f; unsigned u; } v; v.f = x;
  unsigned r = v.u + 0x7FFFu + ((v.u >> 16) & 1u);
  return (u16)(r >> 16);
}
__device__ __forceinline__ float bf2f(u16 h) {
  union { unsigned u; float f; } v; v.u = ((unsigned)h) << 16; return v.f;
}
__device__ __forceinline__ void split3(float x, u16& h, u16& m, u16& l) {
  h = f2bf(x); float r1 = x - bf2f(h);
  m = f2bf(r1); float r2 = r1 - bf2f(m);
  l = f2bf(r2);
}
__device__ __forceinline__ float lsw(float u) {            // 0.909 * u * sigmoid(u)
  return 0.909f * u / (1.f + __expf(-u));
}
__device__ __forceinline__ float tanh_fast(float u) {
  return 1.f - 2.f / (1.f + __expf(2.f * u));
}
__device__ __forceinline__ f32x4 mm(short8 a, short8 b, f32x4 c) {
  return __builtin_amdgcn_mfma_f32_16x16x32_bf16(a, b, c, 0, 0, 0);
}
__device__ __forceinline__ short8 ldfrag(const u16* p) { return *(const short8*)p; }

// Pre-fragment W[K][O] (row-major, ld ldW) into 3 bf16 limbs in MFMA fragment order:
// dst[((nt*KS+ks)*64+lane)*8+e] = W[rowOff + ks*32 + (lane>>4)*8 + e][nt*16 + (lane&15)]
__global__ void frag_w3(const float* __restrict__ W, int KS, int ldW, int rowOff,
                        u16* __restrict__ dh, u16* __restrict__ dm,
                        u16* __restrict__ dl, int nElems) {
  int i = blockIdx.x * blockDim.x + threadIdx.x;
  if (i >= nElems) return;
  int e = i & 7, lane = (i >> 3) & 63, rest = i >> 9;
  int ks = rest % KS, nt = rest / KS;
  int row = rowOff + ks * 32 + ((lane >> 4) * 8) + e;
  int col = nt * 16 + (lane & 15);
  float w = W[row * ldW + col];
  u16 h, m, l; split3(w, h, m, l);
  dh[i] = h; dm[i] = m; dl[i] = l;
}

__global__ __launch_bounds__(512, 1) void sde_gen(
    const float* __restrict__ ts, const float* __restrict__ init_noise,
    const float* __restrict__ dW,
    const float* __restrict__ ib0, const float* __restrict__ ib1, const float* __restrict__ ib2,
    const float* __restrict__ gw0, const float* __restrict__ gb0,
    const float* __restrict__ gb1, const float* __restrict__ gb2,
    const float* __restrict__ rw, const float* __restrict__ rb,
    const u16* __restrict__ fiw0h, const u16* __restrict__ fiw0m, const u16* __restrict__ fiw0l,
    const u16* __restrict__ fiw1h, const u16* __restrict__ fiw1m, const u16* __restrict__ fiw1l,
    const u16* __restrict__ fiw2h, const u16* __restrict__ fiw2m, const u16* __restrict__ fiw2l,
    const u16* __restrict__ fgw0h, const u16* __restrict__ fgw0m, const u16* __restrict__ fgw0l,
    const u16* __restrict__ fgw1h, const u16* __restrict__ fgw1m, const u16* __restrict__ fgw1l,
    const u16* __restrict__ fgw2h, const u16* __restrict__ fgw2m, const u16* __restrict__ fgw2l,
    float* __restrict__ out) {
  extern __shared__ char smem[];
  u16*   s_w1   = (u16*)(smem);            // [3][16384] gw1 limb frags
  u16*   s_ax   = (u16*)(smem + 98304);    // [3][16][72]
  u16*   s_ah0  = (u16*)(smem + 105216);   // [3][16][136]
  u16*   s_ah1  = (u16*)(smem + 118272);   // [3][16][136]
  float* s_z    = (float*)(smem + 131328); // [16][64]
  float* s_zh   = (float*)(smem + 135424); // [16][64]
  float* s_v    = (float*)(smem + 139520); // [16][68]
  float* s_w    = (float*)(smem + 143872); // [16][68]
  float* s_dw   = (float*)(smem + 148224); // [2][16][17]
  float* s_ts   = (float*)(smem + 150400); // [128]
  float* s_gb0  = (float*)(smem + 150912);
  float* s_w0r0 = (float*)(smem + 151424);
  float* s_gb1  = (float*)(smem + 151936);
  float* s_gb2  = (float*)(smem + 152448); // [1024]
  float* s_rw   = (float*)(smem + 156544); // [64]
#define AX(L,r,c)   s_ax [((L)*16+(r))*72 +(c)]
#define AH0(L,r,c)  s_ah0[((L)*16+(r))*136+(c)]
#define AH1(L,r,c)  s_ah1[((L)*16+(r))*136+(c)]
#define ZV(r,c)  s_z [(r)*64+(c)]
#define ZH(r,c)  s_zh[(r)*64+(c)]
#define SV(r,c)  s_v [(r)*68+(c)]
#define SW(r,c)  s_w [(r)*68+(c)]
#define SDW(b,r,c) s_dw[((b)*16+(r))*17+(c)]

  const int tid = threadIdx.x;
  const int wv = tid >> 6;        // 0..7
  const int lane = tid & 63;
  const int l15 = lane & 15, lg = lane >> 4;
  const int R = blockIdx.x * 16;
  const int jrot = blockIdx.x & 7;   // de-correlate W2 L2-line access across blocks

  // ---- one-time loads ----
  for (int i = tid; i < 128; i += 512) {
    s_ts[i] = ts[i]; s_gb0[i] = gb0[i]; s_gb1[i] = gb1[i]; s_w0r0[i] = gw0[i];
  }
  for (int i = tid; i < 1024; i += 512) s_gb2[i] = gb2[i];
  if (tid < 64) s_rw[tid] = rw[tid];
  for (int i = tid; i < 2048; i += 512) {   // gw1 limb frags -> LDS (98304 B)
    ((short8*)s_w1)[i]          = ((const short8*)fgw1h)[i];
    ((short8*)(s_w1+16384))[i]  = ((const short8*)fgw1m)[i];
    ((short8*)(s_w1+32768))[i]  = ((const short8*)fgw1l)[i];
  }
  for (int i = tid; i < 16 * 64; i += 512) {
    int r = i >> 6, k = i & 63;
    float x = init_noise[(R + r) * 64 + k];
    u16 h, m, l; split3(x, h, m, l);
    AX(0,r,k) = h; AX(1,r,k) = m; AX(2,r,k) = l;
  }
  if (tid < 256) { // dWs[0]; zero dWs buf 1
    float sdt = sqrtf(ts[1] - ts[0]);
    int r = tid >> 4, nn = tid & 15;
    SDW(0, r, nn) = dW[(0 * B_TOT + R + r) * 16 + nn] * sdt;
    SDW(1, r, nn) = 0.f;
  }
  __syncthreads();

  // ---------------- initial MLP (bf16x6) ----------------
  { // L1, K=64, tile t = wv (8 tiles)
    f32x4 aA = {0,0,0,0}, aB = {0,0,0,0}, aC = {0,0,0,0};
#pragma unroll
    for (int ks = 0; ks < 2; ++ks) {
      short8 xh = *(const short8*)&AX(0, l15, ks*32 + lg*8);
      short8 xm = *(const short8*)&AX(1, l15, ks*32 + lg*8);
      short8 xl = *(const short8*)&AX(2, l15, ks*32 + lg*8);
      int off = ((wv * 2 + ks) * 64 + lane) * 8;
      short8 bh = ldfrag(fiw0h + off), bm = ldfrag(fiw0m + off), bl = ldfrag(fiw0l + off);
      aA = mm(xh, bh, aA);
      aB = mm(xh, bm, mm(xm, bh, aB));
      aC = mm(xh, bl, mm(xm, bm, mm(xl, bh, aC)));
    }
#pragma unroll
    for (int reg = 0; reg < 4; ++reg) {
      int r = lg * 4 + reg, c = wv * 16 + l15;
      float act = lsw(((aC[reg] + aB[reg]) + aA[reg]) + ib0[c]);
      u16 h, m, l; split3(act, h, m, l);
      AH0(0,r,c) = h; AH0(1,r,c) = m; AH0(2,r,c) = l;
    }
  }
  __syncthreads();
  { // L2, K=128, tile t = wv
    f32x4 aA = {0,0,0,0}, aB = {0,0,0,0}, aC = {0,0,0,0};
#pragma unroll
    for (int ks = 0; ks < 4; ++ks) {
      short8 xh = *(const short8*)&AH0(0, l15, ks*32 + lg*8);
      short8 xm = *(const short8*)&AH0(1, l15, ks*32 + lg*8);
      short8 xl = *(const short8*)&AH0(2, l15, ks*32 + lg*8);
      int off = ((wv * 4 + ks) * 64 + lane) * 8;
      short8 bh = ldfrag(fiw1h + off), bm = ldfrag(fiw1m + off), bl = ldfrag(fiw1l + off);
      aA = mm(xh, bh, aA);
      aB = mm(xh, bm, mm(xm, bh, aB));
      aC = mm(xh, bl, mm(xm, bm, mm(xl, bh, aC)));
    }
#pragma unroll
    for (int reg = 0; reg < 4; ++reg) {
      int r = lg * 4 + reg, c = wv * 16 + l15;
      float act = lsw(((aC[reg] + aB[reg]) + aA[reg]) + ib1[c]);
      u16 h, m, l; split3(act, h, m, l);
      AH1(0,r,c) = h; AH1(1,r,c) = m; AH1(2,r,c) = l;
    }
  }
  __syncthreads();
  if (wv < 4) { // L3 init: O=64, tile wv
    f32x4 aA = {0,0,0,0}, aB = {0,0,0,0}, aC = {0,0,0,0};
#pragma unroll
    for (int ks = 0; ks < 4; ++ks) {
      short8 xh = *(const short8*)&AH1(0, l15, ks*32 + lg*8);
      short8 xm = *(const short8*)&AH1(1, l15, ks*32 + lg*8);
      short8 xl = *(const short8*)&AH1(2, l15, ks*32 + lg*8);
      int off = ((wv * 4 + ks) * 64 + lane) * 8;
      short8 bh = ldfrag(fiw2h + off), bm = ldfrag(fiw2m + off), bl = ldfrag(fiw2l + off);
      aA = mm(xh, bh, aA);
      aB = mm(xh, bm, mm(xm, bh, aB));
      aC = mm(xh, bl, mm(xm, bm, mm(xl, bh, aC)));
    }
#pragma unroll
    for (int reg = 0; reg < 4; ++reg) {
      int r = lg * 4 + reg, c = wv * 16 + l15;
      float x0 = ((aC[reg] + aB[reg]) + aA[reg]) + ib2[c];
      ZV(r,c) = x0; ZH(r,c) = x0;
      u16 h, m, l; split3(x0, h, m, l);
      AX(0,r,c) = h; AX(1,r,c) = m; AX(2,r,c) = l;
    }
  }
  __syncthreads();

  // ---- resident gw0 limbs (24 regs) ----
  short8 g0h[2], g0m[2], g0l[2];
#pragma unroll
  for (int ks = 0; ks < 2; ++ks) {
    int off = ((wv * 2 + ks) * 64 + lane) * 8;
    g0h[ks] = ldfrag(fgw0h + off);
    g0m[ks] = ldfrag(fgw0m + off);
    g0l[ks] = ldfrag(fgw0l + off);
  }

  const float rbv = rb[0];

// W2 tile compute: consumes buffer (WH,WM,WL) for tile ntX
#define L3_COMPUTE(WH, WM, WL, NT)                                              \
  {                                                                             \
    f32x4 aA = {0,0,0,0}, aB = {0,0,0,0}, aC = {0,0,0,0};                       \
    _Pragma("unroll")                                                           \
    for (int ks = 0; ks < 4; ++ks) {                                            \
      aA = mm(WH[ks], bfh[ks], aA);                                             \
      aB = mm(WH[ks], bfm[ks], mm(WM[ks], bfh[ks], aB));                        \
      aC = mm(WH[ks], bfl[ks], mm(WM[ks], bfm[ks], mm(WL[ks], bfh[ks], aC)));   \
    }                                                                           \
    float pw = 0.f, pv = 0.f;                                                   \
    _Pragma("unroll")                                                           \
    for (int reg = 0; reg < 4; ++reg) {                                         \
      int c = (NT) * 16 + lg * 4 + reg;                                         \
      float g = tanh_fast(((aC[reg] + aB[reg]) + aA[reg]) + s_gb2[c]);          \
      pw += g * dw0v[reg];                                                      \
      pv += g * dw1v[reg];                                                      \
    }                                                                           \
    pw += __shfl_xor(pw, 16); pw += __shfl_xor(pw, 32);                         \
    pv += __shfl_xor(pv, 16); pv += __shfl_xor(pv, 32);                         \
    if (lane < 16) { SW(lane, (NT)) = pw; SV(lane, (NT)) = pv; }                \
  }

#define L3_PREFETCH(WH, WM, WL, NT)                                             \
  {                                                                             \
    _Pragma("unroll")                                                           \
    for (int ks = 0; ks < 4; ++ks) {                                            \
      int off = (((NT) * 4 + ks) * 64 + lane) * 8;                              \
      WH[ks] = ldfrag(fgw2h + off);                                             \
      WM[ks] = ldfrag(fgw2m + off);                                             \
      WL[ks] = ldfrag(fgw2l + off);                                             \
    }                                                                           \
  }

  // ---------------- time loop ----------------
  for (int n = 0; n < T_STEPS; ++n) {
    if (n > 0) {
      // phase A: zhat_n = 2z - zhat + v ; z += 0.5 v ; stage x limbs
#pragma unroll
      for (int i = 0; i < 2; ++i) {
        int r = wv * 2 + i, h = lane;
        float z = ZV(r,h), zh = ZH(r,h), v = SV(r,h);
        float zhn = 2.f * z - zh + v;
        ZH(r,h) = zhn;
        u16 hh, mmv, ll; split3(zhn, hh, mmv, ll);
        AX(0,r,h) = hh; AX(1,r,h) = mmv; AX(2,r,h) = ll;
        ZV(r,h) = z + 0.5f * v;
      }
      if (n < T_STEPS - 1 && tid < 256) {
        float sdt = sqrtf(s_ts[n + 1] - s_ts[n]);
        int r = tid >> 4, nn = tid & 15;
        SDW(n & 1, r, nn) = dW[(n * B_TOT + R + r) * 16 + nn] * sdt;
      }
      __syncthreads();
    }
    const float tval = s_ts[n];
    { // L1: h0 = lsw(x@gw0[1:] + gb0 + t*gw0[0]), tile t = wv, gw0 resident
      f32x4 aA = {0,0,0,0}, aB = {0,0,0,0}, aC = {0,0,0,0};
#pragma unroll
      for (int ks = 0; ks < 2; ++ks) {
        short8 xh = *(const short8*)&AX(0, l15, ks*32 + lg*8);
        short8 xm = *(const short8*)&AX(1, l15, ks*32 + lg*8);
        short8 xl = *(const short8*)&AX(2, l15, ks*32 + lg*8);
        aA = mm(xh, g0h[ks], aA);
        aB = mm(xh, g0m[ks], mm(xm, g0h[ks], aB));
        aC = mm(xh, g0l[ks], mm(xm, g0m[ks], mm(xl, g0h[ks], aC)));
      }
#pragma unroll
      for (int reg = 0; reg < 4; ++reg) {
        int r = lg * 4 + reg, c = wv * 16 + l15;
        float act = lsw(((aC[reg] + aB[reg]) + aA[reg]) + s_gb0[c] + tval * s_w0r0[c]);
        u16 h, m, l; split3(act, h, m, l);
        AH0(0,r,c) = h; AH0(1,r,c) = m; AH0(2,r,c) = l;
      }
    }
    __syncthreads();
    short8 whA[4], wmA[4], wlA[4], whB[4], wmB[4], wlB[4];  // j-loop double buffer
    { // L2: h1 = lsw(h0@gw1 + gb1), tile t = wv, gw1 limbs from LDS
      // issue j=0 W2 prefetch first: global-only, hidden under the L2 MFMAs
      L3_PREFETCH(whA, wmA, wlA, wv * 8 + jrot);
      f32x4 aA = {0,0,0,0}, aB = {0,0,0,0}, aC = {0,0,0,0};
#pragma unroll
      for (int ks = 0; ks < 4; ++ks) {
        short8 xh = *(const short8*)&AH0(0, l15, ks*32 + lg*8);
        short8 xm = *(const short8*)&AH0(1, l15, ks*32 + lg*8);
        short8 xl = *(const short8*)&AH0(2, l15, ks*32 + lg*8);
        int off = ((wv * 4 + ks) * 64 + lane) * 8;
        short8 bh = *(const short8*)&s_w1[off];
        short8 bm = *(const short8*)&s_w1[16384 + off];
        short8 bl = *(const short8*)&s_w1[32768 + off];
        aA = mm(xh, bh, aA);
        aB = mm(xh, bm, mm(xm, bh, aB));
        aC = mm(xh, bl, mm(xm, bm, mm(xl, bh, aC)));
      }
#pragma unroll
      for (int reg = 0; reg < 4; ++reg) {
        int r = lg * 4 + reg, c = wv * 16 + l15;
        float act = lsw(((aC[reg] + aB[reg]) + aA[reg]) + s_gb1[c]);
        u16 h, m, l; split3(act, h, m, l);
        AH1(0,r,c) = h; AH1(1,r,c) = m; AH1(2,r,c) = l;
      }
    }
    __syncthreads();
    // L3 transposed (D' = W2^T h1^T): software-pipelined W2 stream (A/B buffers)
    float dw0v[4], dw1v[4];
#pragma unroll
    for (int reg = 0; reg < 4; ++reg) {
      dw0v[reg] = SDW((n - 1) & 1, l15, lg * 4 + reg);
      dw1v[reg] = SDW(n & 1,       l15, lg * 4 + reg);
    }
    short8 bfh[4], bfm[4], bfl[4];
#pragma unroll
    for (int ks = 0; ks < 4; ++ks) {
      bfh[ks] = *(const short8*)&AH1(0, l15, ks*32 + lg*8);
      bfm[ks] = *(const short8*)&AH1(1, l15, ks*32 + lg*8);
      bfl[ks] = *(const short8*)&AH1(2, l15, ks*32 + lg*8);
    }
#pragma unroll 1
    for (int j = 0; j < 8; j += 2) {
      const int ntA = wv * 8 + ((j + jrot) & 7);
      const int ntB = wv * 8 + ((j + 1 + jrot) & 7);
      L3_PREFETCH(whB, wmB, wlB, ntB);       // prefetch j+1 while computing j
      L3_COMPUTE(whA, wmA, wlA, ntA);
      if (j < 6) {
        const int ntA2 = wv * 8 + ((j + 2 + jrot) & 7);
        L3_PREFETCH(whA, wmA, wlA, ntA2);    // prefetch j+2 while computing j+1
      }
      L3_COMPUTE(whB, wmB, wlB, ntB);
    }
    __syncthreads();
    // phase D: z_n = z + 0.5 w ; emit (ts, z.rw + rb)
#pragma unroll
    for (int i = 0; i < 2; ++i) {
      int r = wv * 2 + i, h = lane;
      float z = ZV(r,h);
      if (n > 0) { z += 0.5f * SW(r,h); ZV(r,h) = z; }
      float p = z * s_rw[h];
#pragma unroll
      for (int off = 32; off >= 1; off >>= 1) p += __shfl_xor(p, off);
      if (lane == 0) {
        int o = ((R + r) * T_STEPS + n) * 2;
        out[o] = tval; out[o + 1] = p + rbv;
      }
    }
  }
}

extern "C" void kernel_launch(void* const* d_in, const int* in_sizes, int n_in,
                              void* d_out, int out_size, void* d_ws, size_t ws_size,
                              hipStream_t stream) {
  (void)in_sizes; (void)n_in; (void)out_size; (void)ws_size;
  const float* ts = (const float*)d_in[0];
  const float* init_noise = (const float*)d_in[2];
  const float* dW  = (const float*)d_in[3];
  const float* iw0 = (const float*)d_in[4];
  const float* ib0 = (const float*)d_in[5];
  const float* iw1 = (const float*)d_in[6];
  const float* ib1 = (const float*)d_in[7];
  const float* iw2 = (const float*)d_in[8];
  const float* ib2 = (const float*)d_in[9];
  const float* gw0 = (const float*)d_in[10];
  const float* gb0 = (const float*)d_in[11];
  const float* gw1 = (const float*)d_in[12];
  const float* gb1 = (const float*)d_in[13];
  const float* gw2 = (const float*)d_in[14];
  const float* gb2 = (const float*)d_in[15];
  const float* rw  = (const float*)d_in[16];
  const float* rb  = (const float*)d_in[17];

  u16* ws = (u16*)d_ws;
  const int LO = 188416;  // elems per limb block
  u16* fiw0h = ws + 0;      u16* fiw0m = ws + LO + 0;      u16* fiw0l = ws + 2*LO + 0;
  u16* fiw1h = ws + 8192;   u16* fiw1m = ws + LO + 8192;   u16* fiw1l = ws + 2*LO + 8192;
  u16* fiw2h = ws + 24576;  u16* fiw2m = ws + LO + 24576;  u16* fiw2l = ws + 2*LO + 24576;
  u16* fgw0h = ws + 32768;  u16* fgw0m = ws + LO + 32768;  u16* fgw0l = ws + 2*LO + 32768;
  u16* fgw1h = ws + 40960;  u16* fgw1m = ws + LO + 40960;  u16* fgw1l = ws + 2*LO + 40960;
  u16* fgw2h = ws + 57344;  u16* fgw2m = ws + LO + 57344;  u16* fgw2l = ws + 2*LO + 57344;

  frag_w3<<<32,  256, 0, stream>>>(iw0, 2, 128, 0, fiw0h, fiw0m, fiw0l, 8192);
  frag_w3<<<64,  256, 0, stream>>>(iw1, 4, 128, 0, fiw1h, fiw1m, fiw1l, 16384);
  frag_w3<<<32,  256, 0, stream>>>(iw2, 4, 64,  0, fiw2h, fiw2m, fiw2l, 8192);
  frag_w3<<<32,  256, 0, stream>>>(gw0, 2, 128, 1, fgw0h, fgw0m, fgw0l, 8192);
  frag_w3<<<64,  256, 0, stream>>>(gw1, 4, 128, 0, fgw1h, fgw1m, fgw1l, 16384);
  frag_w3<<<512, 256, 0, stream>>>(gw2, 4, 1024, 0, fgw2h, fgw2m, fgw2l, 131072);

  hipFuncSetAttribute((const void*)sde_gen,
                      hipFuncAttributeMaxDynamicSharedMemorySize, SMEM_BYTES);
  sde_gen<<<256, 512, SMEM_BYTES, stream>>>(
      ts, init_noise, dW, ib0, ib1, ib2, gw0, gb0, gb1, gb2, rw, rb,
      fiw0h, fiw0m, fiw0l, fiw1h, fiw1m, fiw1l, fiw2h, fiw2m, fiw2l,
      fgw0h, fgw0m, fgw0l, fgw1h, fgw1m, fgw1l, fgw2h, fgw2m, fgw2l,
      (float*)d_out);
}

// Round 11
// 1105.078 us; speedup vs baseline: 1.4140x; 1.4140x over previous
//
#include <hip/hip_runtime.h>

typedef unsigned short u16;
typedef _Float16 f16;
typedef __attribute__((ext_vector_type(8))) _Float16 f16x8;
typedef __attribute__((ext_vector_type(4))) float f32x4;

#define B_TOT 4096
#define T_STEPS 128
#define SMEM_BYTES 113024
#define LSCALE 2048.f
#define LINV   4.8828125e-4f   // 1/2048, exact

__device__ __forceinline__ u16 f2h(float x) {
  union { f16 h; u16 u; } v; v.h = (f16)x; return v.u;
}
__device__ __forceinline__ float h2f(u16 b) {
  union { u16 u; f16 h; } v; v.u = b; return (float)v.h;
}
// 2-limb fp16 split with scaled low limb: x ~= h + l/2048 to ~2^-22 rel.
__device__ __forceinline__ void split2(float x, u16& h, u16& l) {
  h = f2h(x);
  float r = x - h2f(h);
  l = f2h(r * LSCALE);
}
__device__ __forceinline__ float lsw(float u) {            // 0.909 * u * sigmoid(u)
  return 0.909f * u / (1.f + __expf(-u));
}
__device__ __forceinline__ float tanh_fast(float u) {
  return 1.f - 2.f / (1.f + __expf(2.f * u));
}
__device__ __forceinline__ f32x4 mmh(f16x8 a, f16x8 b, f32x4 c) {
  return __builtin_amdgcn_mfma_f32_16x16x32_f16(a, b, c, 0, 0, 0);
}
__device__ __forceinline__ f16x8 ldfrag(const u16* p) { return *(const f16x8*)p; }

// Pre-fragment W[K][O] (row-major, ld ldW) into 2 fp16 limbs in MFMA fragment order:
// dst[((nt*KS+ks)*64+lane)*8+e] = W[rowOff + ks*32 + (lane>>4)*8 + e][nt*16 + (lane&15)]
__global__ void frag_w2(const float* __restrict__ W, int KS, int ldW, int rowOff,
                        u16* __restrict__ dh, u16* __restrict__ dl, int nElems) {
  int i = blockIdx.x * blockDim.x + threadIdx.x;
  if (i >= nElems) return;
  int e = i & 7, lane = (i >> 3) & 63, rest = i >> 9;
  int ks = rest % KS, nt = rest / KS;
  int row = rowOff + ks * 32 + ((lane >> 4) * 8) + e;
  int col = nt * 16 + (lane & 15);
  float w = W[row * ldW + col];
  u16 h, l; split2(w, h, l);
  dh[i] = h; dl[i] = l;
}

__global__ __launch_bounds__(512, 1) void sde_gen(
    const float* __restrict__ ts, const float* __restrict__ init_noise,
    const float* __restrict__ dW,
    const float* __restrict__ ib0, const float* __restrict__ ib1, const float* __restrict__ ib2,
    const float* __restrict__ gw0, const float* __restrict__ gb0,
    const float* __restrict__ gb1, const float* __restrict__ gb2,
    const float* __restrict__ rw, const float* __restrict__ rb,
    const u16* __restrict__ fiw0h, const u16* __restrict__ fiw0l,
    const u16* __restrict__ fiw1h, const u16* __restrict__ fiw1l,
    const u16* __restrict__ fiw2h, const u16* __restrict__ fiw2l,
    const u16* __restrict__ fgw0h, const u16* __restrict__ fgw0l,
    const u16* __restrict__ fgw1h, const u16* __restrict__ fgw1l,
    const u16* __restrict__ fgw2h, const u16* __restrict__ fgw2l,
    float* __restrict__ out) {
  extern __shared__ char smem[];
  u16*   s_w1h  = (u16*)(smem);            // [16384] gw1 hi frags
  u16*   s_w1l  = (u16*)(smem + 32768);    // [16384] gw1 lo frags
  u16*   s_ax   = (u16*)(smem + 65536);    // [2][16][72]
  u16*   s_ah0  = (u16*)(smem + 70144);    // [2][16][136]
  u16*   s_ah1  = (u16*)(smem + 78848);    // [2][16][136]
  float* s_z    = (float*)(smem + 87552);  // [16][64]
  float* s_zh   = (float*)(smem + 91648);  // [16][64]
  float* s_v    = (float*)(smem + 95744);  // [16][68]
  float* s_w    = (float*)(smem + 100096); // [16][68]
  float* s_dw   = (float*)(smem + 104448); // [2][16][17]
  float* s_ts   = (float*)(smem + 106624); // [128]
  float* s_gb0  = (float*)(smem + 107136);
  float* s_w0r0 = (float*)(smem + 107648);
  float* s_gb1  = (float*)(smem + 108160);
  float* s_gb2  = (float*)(smem + 108672); // [1024]
  float* s_rw   = (float*)(smem + 112768); // [64]
#define AX(L,r,c)   s_ax [((L)*16+(r))*72 +(c)]
#define AH0(L,r,c)  s_ah0[((L)*16+(r))*136+(c)]
#define AH1(L,r,c)  s_ah1[((L)*16+(r))*136+(c)]
#define ZV(r,c)  s_z [(r)*64+(c)]
#define ZH(r,c)  s_zh[(r)*64+(c)]
#define SV(r,c)  s_v [(r)*68+(c)]
#define SW(r,c)  s_w [(r)*68+(c)]
#define SDW(b,r,c) s_dw[((b)*16+(r))*17+(c)]

  const int tid = threadIdx.x;
  const int wv = tid >> 6;        // 0..7
  const int lane = tid & 63;
  const int l15 = lane & 15, lg = lane >> 4;
  const int R = blockIdx.x * 16;
  const int jrot = blockIdx.x & 7;   // de-correlate W2 L2-line access across blocks

  // ---- one-time loads ----
  for (int i = tid; i < 128; i += 512) {
    s_ts[i] = ts[i]; s_gb0[i] = gb0[i]; s_gb1[i] = gb1[i]; s_w0r0[i] = gw0[i];
  }
  for (int i = tid; i < 1024; i += 512) s_gb2[i] = gb2[i];
  if (tid < 64) s_rw[tid] = rw[tid];
  for (int i = tid; i < 2048; i += 512) {   // gw1 limb frags -> LDS (64 KB)
    ((f16x8*)s_w1h)[i] = ((const f16x8*)fgw1h)[i];
    ((f16x8*)s_w1l)[i] = ((const f16x8*)fgw1l)[i];
  }
  for (int i = tid; i < 16 * 64; i += 512) {
    int r = i >> 6, k = i & 63;
    float x = init_noise[(R + r) * 64 + k];
    u16 h, l; split2(x, h, l);
    AX(0,r,k) = h; AX(1,r,k) = l;
  }
  if (tid < 256) { // dWs[0]; zero dWs buf 1
    float sdt = sqrtf(ts[1] - ts[0]);
    int r = tid >> 4, nn = tid & 15;
    SDW(0, r, nn) = dW[(0 * B_TOT + R + r) * 16 + nn] * sdt;
    SDW(1, r, nn) = 0.f;
  }
  __syncthreads();

  // ---------------- initial MLP (fp16x3-product) ----------------
  { // L1, K=64, tile t = wv (8 tiles)
    f32x4 aA = {0,0,0,0}, aB = {0,0,0,0};
#pragma unroll
    for (int ks = 0; ks < 2; ++ks) {
      f16x8 xh = *(const f16x8*)&AX(0, l15, ks*32 + lg*8);
      f16x8 xl = *(const f16x8*)&AX(1, l15, ks*32 + lg*8);
      int off = ((wv * 2 + ks) * 64 + lane) * 8;
      f16x8 bh = ldfrag(fiw0h + off), bl = ldfrag(fiw0l + off);
      aA = mmh(xh, bh, aA);
      aB = mmh(xh, bl, mmh(xl, bh, aB));
    }
#pragma unroll
    for (int reg = 0; reg < 4; ++reg) {
      int r = lg * 4 + reg, c = wv * 16 + l15;
      float act = lsw((aA[reg] + aB[reg] * LINV) + ib0[c]);
      u16 h, l; split2(act, h, l);
      AH0(0,r,c) = h; AH0(1,r,c) = l;
    }
  }
  __syncthreads();
  { // L2, K=128, tile t = wv
    f32x4 aA = {0,0,0,0}, aB = {0,0,0,0};
#pragma unroll
    for (int ks = 0; ks < 4; ++ks) {
      f16x8 xh = *(const f16x8*)&AH0(0, l15, ks*32 + lg*8);
      f16x8 xl = *(const f16x8*)&AH0(1, l15, ks*32 + lg*8);
      int off = ((wv * 4 + ks) * 64 + lane) * 8;
      f16x8 bh = ldfrag(fiw1h + off), bl = ldfrag(fiw1l + off);
      aA = mmh(xh, bh, aA);
      aB = mmh(xh, bl, mmh(xl, bh, aB));
    }
#pragma unroll
    for (int reg = 0; reg < 4; ++reg) {
      int r = lg * 4 + reg, c = wv * 16 + l15;
      float act = lsw((aA[reg] + aB[reg] * LINV) + ib1[c]);
      u16 h, l; split2(act, h, l);
      AH1(0,r,c) = h; AH1(1,r,c) = l;
    }
  }
  __syncthreads();
  if (wv < 4) { // L3 init: O=64, tile wv
    f32x4 aA = {0,0,0,0}, aB = {0,0,0,0};
#pragma unroll
    for (int ks = 0; ks < 4; ++ks) {
      f16x8 xh = *(const f16x8*)&AH1(0, l15, ks*32 + lg*8);
      f16x8 xl = *(const f16x8*)&AH1(1, l15, ks*32 + lg*8);
      int off = ((wv * 4 + ks) * 64 + lane) * 8;
      f16x8 bh = ldfrag(fiw2h + off), bl = ldfrag(fiw2l + off);
      aA = mmh(xh, bh, aA);
      aB = mmh(xh, bl, mmh(xl, bh, aB));
    }
#pragma unroll
    for (int reg = 0; reg < 4; ++reg) {
      int r = lg * 4 + reg, c = wv * 16 + l15;
      float x0 = (aA[reg] + aB[reg] * LINV) + ib2[c];
      ZV(r,c) = x0; ZH(r,c) = x0;
      u16 h, l; split2(x0, h, l);
      AX(0,r,c) = h; AX(1,r,c) = l;
    }
  }
  __syncthreads();

  const float rbv = rb[0];

  // ---------------- time loop ----------------
  for (int n = 0; n < T_STEPS; ++n) {
    if (n > 0) {
      // phase A: zhat_n = 2z - zhat + v ; z += 0.5 v ; stage x limbs
#pragma unroll
      for (int i = 0; i < 2; ++i) {
        int r = wv * 2 + i, h = lane;
        float z = ZV(r,h), zh = ZH(r,h), v = SV(r,h);
        float zhn = 2.f * z - zh + v;
        ZH(r,h) = zhn;
        u16 hh, ll; split2(zhn, hh, ll);
        AX(0,r,h) = hh; AX(1,r,h) = ll;
        ZV(r,h) = z + 0.5f * v;
      }
      if (n < T_STEPS - 1 && tid < 256) {
        float sdt = sqrtf(s_ts[n + 1] - s_ts[n]);
        int r = tid >> 4, nn = tid & 15;
        SDW(n & 1, r, nn) = dW[(n * B_TOT + R + r) * 16 + nn] * sdt;
      }
      __syncthreads();
    }
    const float tval = s_ts[n];
    { // L1: h0 = lsw(x@gw0[1:] + gb0 + t*gw0[0]), tile t = wv, gw0 streamed (L2-hit)
      f32x4 aA = {0,0,0,0}, aB = {0,0,0,0};
#pragma unroll
      for (int ks = 0; ks < 2; ++ks) {
        f16x8 xh = *(const f16x8*)&AX(0, l15, ks*32 + lg*8);
        f16x8 xl = *(const f16x8*)&AX(1, l15, ks*32 + lg*8);
        int off = ((wv * 2 + ks) * 64 + lane) * 8;
        f16x8 bh = ldfrag(fgw0h + off);
        f16x8 bl = ldfrag(fgw0l + off);
        aA = mmh(xh, bh, aA);
        aB = mmh(xh, bl, mmh(xl, bh, aB));
      }
#pragma unroll
      for (int reg = 0; reg < 4; ++reg) {
        int r = lg * 4 + reg, c = wv * 16 + l15;
        float act = lsw((aA[reg] + aB[reg] * LINV) + s_gb0[c] + tval * s_w0r0[c]);
        u16 h, l; split2(act, h, l);
        AH0(0,r,c) = h; AH0(1,r,c) = l;
      }
    }
    __syncthreads();
    { // L2: h1 = lsw(h0@gw1 + gb1), tile t = wv, gw1 limbs from LDS
      f32x4 aA = {0,0,0,0}, aB = {0,0,0,0};
#pragma unroll
      for (int ks = 0; ks < 4; ++ks) {
        f16x8 xh = *(const f16x8*)&AH0(0, l15, ks*32 + lg*8);
        f16x8 xl = *(const f16x8*)&AH0(1, l15, ks*32 + lg*8);
        int off = ((wv * 4 + ks) * 64 + lane) * 8;
        f16x8 bh = *(const f16x8*)&s_w1h[off];
        f16x8 bl = *(const f16x8*)&s_w1l[off];
        aA = mmh(xh, bh, aA);
        aB = mmh(xh, bl, mmh(xl, bh, aB));
      }
#pragma unroll
      for (int reg = 0; reg < 4; ++reg) {
        int r = lg * 4 + reg, c = wv * 16 + l15;
        float act = lsw((aA[reg] + aB[reg] * LINV) + s_gb1[c]);
        u16 h, l; split2(act, h, l);
        AH1(0,r,c) = h; AH1(1,r,c) = l;
      }
    }
    __syncthreads();
    // L3 transposed (D' = W2^T h1^T): W2 limbs streamed, single-buffered,
    // runtime j-loop (keeps register pressure minimal -> no spills, cf. R9).
    float dw0v[4], dw1v[4];
#pragma unroll
    for (int reg = 0; reg < 4; ++reg) {
      dw0v[reg] = SDW((n - 1) & 1, l15, lg * 4 + reg);
      dw1v[reg] = SDW(n & 1,       l15, lg * 4 + reg);
    }
    f16x8 bfh[4], bfl[4];
#pragma unroll
    for (int ks = 0; ks < 4; ++ks) {
      bfh[ks] = *(const f16x8*)&AH1(0, l15, ks*32 + lg*8);
      bfl[ks] = *(const f16x8*)&AH1(1, l15, ks*32 + lg*8);
    }
#pragma unroll 1
    for (int j = 0; j < 8; ++j) {
      const int nt = wv * 8 + ((j + jrot) & 7);
      f16x8 wh[4], wl[4];                  // 32 transient regs, single-buffered
#pragma unroll
      for (int ks = 0; ks < 4; ++ks) {
        int off = ((nt * 4 + ks) * 64 + lane) * 8;
        wh[ks] = ldfrag(fgw2h + off);
        wl[ks] = ldfrag(fgw2l + off);
      }
      f32x4 aA = {0,0,0,0}, aB = {0,0,0,0};
#pragma unroll
      for (int ks = 0; ks < 4; ++ks) {
        aA = mmh(wh[ks], bfh[ks], aA);
        aB = mmh(wh[ks], bfl[ks], mmh(wl[ks], bfh[ks], aB));
      }
      float pw = 0.f, pv = 0.f;
#pragma unroll
      for (int reg = 0; reg < 4; ++reg) {
        int c = nt * 16 + lg * 4 + reg;
        float g = tanh_fast((aA[reg] + aB[reg] * LINV) + s_gb2[c]);
        pw += g * dw0v[reg];
        pv += g * dw1v[reg];
      }
      pw += __shfl_xor(pw, 16); pw += __shfl_xor(pw, 32);
      pv += __shfl_xor(pv, 16); pv += __shfl_xor(pv, 32);
      if (lane < 16) { SW(lane, nt) = pw; SV(lane, nt) = pv; }
    }
    __syncthreads();
    // phase D: z_n = z + 0.5 w ; emit (ts, z.rw + rb)
#pragma unroll
    for (int i = 0; i < 2; ++i) {
      int r = wv * 2 + i, h = lane;
      float z = ZV(r,h);
      if (n > 0) { z += 0.5f * SW(r,h); ZV(r,h) = z; }
      float p = z * s_rw[h];
#pragma unroll
      for (int off = 32; off >= 1; off >>= 1) p += __shfl_xor(p, off);
      if (lane == 0) {
        int o = ((R + r) * T_STEPS + n) * 2;
        out[o] = tval; out[o + 1] = p + rbv;
      }
    }
  }
}

extern "C" void kernel_launch(void* const* d_in, const int* in_sizes, int n_in,
                              void* d_out, int out_size, void* d_ws, size_t ws_size,
                              hipStream_t stream) {
  (void)in_sizes; (void)n_in; (void)out_size; (void)ws_size;
  const float* ts = (const float*)d_in[0];
  const float* init_noise = (const float*)d_in[2];
  const float* dW  = (const float*)d_in[3];
  const float* iw0 = (const float*)d_in[4];
  const float* ib0 = (const float*)d_in[5];
  const float* iw1 = (const float*)d_in[6];
  const float* ib1 = (const float*)d_in[7];
  const float* iw2 = (const float*)d_in[8];
  const float* ib2 = (const float*)d_in[9];
  const float* gw0 = (const float*)d_in[10];
  const float* gb0 = (const float*)d_in[11];
  const float* gw1 = (const float*)d_in[12];
  const float* gb1 = (const float*)d_in[13];
  const float* gw2 = (const float*)d_in[14];
  const float* gb2 = (const float*)d_in[15];
  const float* rw  = (const float*)d_in[16];
  const float* rb  = (const float*)d_in[17];

  u16* ws = (u16*)d_ws;
  const int LO = 188416;  // elems per limb block
  u16* fiw0h = ws + 0;      u16* fiw0l = ws + LO + 0;
  u16* fiw1h = ws + 8192;   u16* fiw1l = ws + LO + 8192;
  u16* fiw2h = ws + 24576;  u16* fiw2l = ws + LO + 24576;
  u16* fgw0h = ws + 32768;  u16* fgw0l = ws + LO + 32768;
  u16* fgw1h = ws + 40960;  u16* fgw1l = ws + LO + 40960;
  u16* fgw2h = ws + 57344;  u16* fgw2l = ws + LO + 57344;

  frag_w2<<<32,  256, 0, stream>>>(iw0, 2, 128, 0, fiw0h, fiw0l, 8192);
  frag_w2<<<64,  256, 0, stream>>>(iw1, 4, 128, 0, fiw1h, fiw1l, 16384);
  frag_w2<<<32,  256, 0, stream>>>(iw2, 4, 64,  0, fiw2h, fiw2l, 8192);
  frag_w2<<<32,  256, 0, stream>>>(gw0, 2, 128, 1, fgw0h, fgw0l, 8192);
  frag_w2<<<64,  256, 0, stream>>>(gw1, 4, 128, 0, fgw1h, fgw1l, 16384);
  frag_w2<<<512, 256, 0, stream>>>(gw2, 4, 1024, 0, fgw2h, fgw2l, 131072);

  hipFuncSetAttribute((const void*)sde_gen,
                      hipFuncAttributeMaxDynamicSharedMemorySize, SMEM_BYTES);
  sde_gen<<<256, 512, SMEM_BYTES, stream>>>(
      ts, init_noise, dW, ib0, ib1, ib2, gw0, gb0, gb1, gb2, rw, rb,
      fiw0h, fiw0l, fiw1h, fiw1l, fiw2h, fiw2l,
      fgw0h, fgw0l, fgw1h, fgw1l, fgw2h, fgw2l,
      (float*)d_out);
}

// Round 12
// 976.640 us; speedup vs baseline: 1.6000x; 1.1315x over previous
//
#include <hip/hip_runtime.h>

typedef unsigned short u16;
typedef _Float16 f16;
typedef __attribute__((ext_vector_type(8))) _Float16 f16x8;
typedef __attribute__((ext_vector_type(4))) float f32x4;

#define B_TOT 4096
#define T_STEPS 128
#define SMEM_BYTES 113024
#define LSCALE 2048.f
#define LINV   4.8828125e-4f   // 1/2048, exact

__device__ __forceinline__ u16 f2h(float x) {
  union { f16 h; u16 u; } v; v.h = (f16)x; return v.u;
}
__device__ __forceinline__ float h2f(u16 b) {
  union { u16 u; f16 h; } v; v.u = b; return (float)v.h;
}
// 2-limb fp16 split with scaled low limb: x ~= h + l/2048 to ~2^-22 rel.
__device__ __forceinline__ void split2(float x, u16& h, u16& l) {
  h = f2h(x);
  float r = x - h2f(h);
  l = f2h(r * LSCALE);
}
__device__ __forceinline__ float lsw(float u) {            // 0.909 * u * sigmoid(u)
  return 0.909f * u / (1.f + __expf(-u));
}
__device__ __forceinline__ float tanh_fast(float u) {
  return 1.f - 2.f / (1.f + __expf(2.f * u));
}
__device__ __forceinline__ f32x4 mmh(f16x8 a, f16x8 b, f32x4 c) {
  return __builtin_amdgcn_mfma_f32_16x16x32_f16(a, b, c, 0, 0, 0);
}
__device__ __forceinline__ f16x8 ldfrag(const u16* p) { return *(const f16x8*)p; }

// Pre-fragment W[K][O] (row-major, ld ldW) into 2 fp16 limbs in MFMA fragment order:
// dst[((nt*KS+ks)*64+lane)*8+e] = W[rowOff + ks*32 + (lane>>4)*8 + e][nt*16 + (lane&15)]
__global__ void frag_w2(const float* __restrict__ W, int KS, int ldW, int rowOff,
                        u16* __restrict__ dh, u16* __restrict__ dl, int nElems) {
  int i = blockIdx.x * blockDim.x + threadIdx.x;
  if (i >= nElems) return;
  int e = i & 7, lane = (i >> 3) & 63, rest = i >> 9;
  int ks = rest % KS, nt = rest / KS;
  int row = rowOff + ks * 32 + ((lane >> 4) * 8) + e;
  int col = nt * 16 + (lane & 15);
  float w = W[row * ldW + col];
  u16 h, l; split2(w, h, l);
  dh[i] = h; dl[i] = l;
}

__global__ __launch_bounds__(512, 1) void sde_gen(
    const float* __restrict__ ts, const float* __restrict__ init_noise,
    const float* __restrict__ dW,
    const float* __restrict__ ib0, const float* __restrict__ ib1, const float* __restrict__ ib2,
    const float* __restrict__ gw0, const float* __restrict__ gb0,
    const float* __restrict__ gb1, const float* __restrict__ gb2,
    const float* __restrict__ rw, const float* __restrict__ rb,
    const u16* __restrict__ fiw0h, const u16* __restrict__ fiw0l,
    const u16* __restrict__ fiw1h, const u16* __restrict__ fiw1l,
    const u16* __restrict__ fiw2h, const u16* __restrict__ fiw2l,
    const u16* __restrict__ fgw0h, const u16* __restrict__ fgw0l,
    const u16* __restrict__ fgw1h, const u16* __restrict__ fgw1l,
    const u16* __restrict__ fgw2h, const u16* __restrict__ fgw2l,
    float* __restrict__ out) {
  extern __shared__ char smem[];
  u16*   s_w1h  = (u16*)(smem);            // [16384] gw1 hi frags
  u16*   s_w1l  = (u16*)(smem + 32768);    // [16384] gw1 lo frags
  u16*   s_ax   = (u16*)(smem + 65536);    // [2][16][72]
  u16*   s_ah0  = (u16*)(smem + 70144);    // [2][16][136]
  u16*   s_ah1  = (u16*)(smem + 78848);    // [2][16][136]
  float* s_z    = (float*)(smem + 87552);  // [16][64]
  float* s_zh   = (float*)(smem + 91648);  // [16][64]
  float* s_v    = (float*)(smem + 95744);  // [16][68]
  float* s_w    = (float*)(smem + 100096); // [16][68]
  float* s_dw   = (float*)(smem + 104448); // [2][16][17]
  float* s_ts   = (float*)(smem + 106624); // [128]
  float* s_gb0  = (float*)(smem + 107136);
  float* s_w0r0 = (float*)(smem + 107648);
  float* s_gb1  = (float*)(smem + 108160);
  float* s_gb2  = (float*)(smem + 108672); // [1024]
  float* s_rw   = (float*)(smem + 112768); // [64]
#define AX(L,r,c)   s_ax [((L)*16+(r))*72 +(c)]
#define AH0(L,r,c)  s_ah0[((L)*16+(r))*136+(c)]
#define AH1(L,r,c)  s_ah1[((L)*16+(r))*136+(c)]
#define ZV(r,c)  s_z [(r)*64+(c)]
#define ZH(r,c)  s_zh[(r)*64+(c)]
#define SV(r,c)  s_v [(r)*68+(c)]
#define SW(r,c)  s_w [(r)*68+(c)]
#define SDW(b,r,c) s_dw[((b)*16+(r))*17+(c)]

  const int tid = threadIdx.x;
  const int wv = tid >> 6;        // 0..7
  const int lane = tid & 63;
  const int l15 = lane & 15, lg = lane >> 4;
  const int R = blockIdx.x * 16;
  const int jrot = blockIdx.x & 7;   // de-correlate W2 L2-line access across blocks

  // ---- one-time loads ----
  for (int i = tid; i < 128; i += 512) {
    s_ts[i] = ts[i]; s_gb0[i] = gb0[i]; s_gb1[i] = gb1[i]; s_w0r0[i] = gw0[i];
  }
  for (int i = tid; i < 1024; i += 512) s_gb2[i] = gb2[i];
  if (tid < 64) s_rw[tid] = rw[tid];
  for (int i = tid; i < 2048; i += 512) {   // gw1 limb frags -> LDS (64 KB)
    ((f16x8*)s_w1h)[i] = ((const f16x8*)fgw1h)[i];
    ((f16x8*)s_w1l)[i] = ((const f16x8*)fgw1l)[i];
  }
  for (int i = tid; i < 16 * 64; i += 512) {
    int r = i >> 6, k = i & 63;
    float x = init_noise[(R + r) * 64 + k];
    u16 h, l; split2(x, h, l);
    AX(0,r,k) = h; AX(1,r,k) = l;
  }
  if (tid < 256) { // dWs[0]; zero dWs buf 1
    float sdt = sqrtf(ts[1] - ts[0]);
    int r = tid >> 4, nn = tid & 15;
    SDW(0, r, nn) = dW[(0 * B_TOT + R + r) * 16 + nn] * sdt;
    SDW(1, r, nn) = 0.f;
  }
  __syncthreads();

  // ---------------- initial MLP (fp16x3-product) ----------------
  { // L1, K=64, tile t = wv (8 tiles)
    f32x4 aA = {0,0,0,0}, aB = {0,0,0,0};
#pragma unroll
    for (int ks = 0; ks < 2; ++ks) {
      f16x8 xh = *(const f16x8*)&AX(0, l15, ks*32 + lg*8);
      f16x8 xl = *(const f16x8*)&AX(1, l15, ks*32 + lg*8);
      int off = ((wv * 2 + ks) * 64 + lane) * 8;
      f16x8 bh = ldfrag(fiw0h + off), bl = ldfrag(fiw0l + off);
      aA = mmh(xh, bh, aA);
      aB = mmh(xh, bl, mmh(xl, bh, aB));
    }
#pragma unroll
    for (int reg = 0; reg < 4; ++reg) {
      int r = lg * 4 + reg, c = wv * 16 + l15;
      float act = lsw((aA[reg] + aB[reg] * LINV) + ib0[c]);
      u16 h, l; split2(act, h, l);
      AH0(0,r,c) = h; AH0(1,r,c) = l;
    }
  }
  __syncthreads();
  { // L2, K=128, tile t = wv
    f32x4 aA = {0,0,0,0}, aB = {0,0,0,0};
#pragma unroll
    for (int ks = 0; ks < 4; ++ks) {
      f16x8 xh = *(const f16x8*)&AH0(0, l15, ks*32 + lg*8);
      f16x8 xl = *(const f16x8*)&AH0(1, l15, ks*32 + lg*8);
      int off = ((wv * 4 + ks) * 64 + lane) * 8;
      f16x8 bh = ldfrag(fiw1h + off), bl = ldfrag(fiw1l + off);
      aA = mmh(xh, bh, aA);
      aB = mmh(xh, bl, mmh(xl, bh, aB));
    }
#pragma unroll
    for (int reg = 0; reg < 4; ++reg) {
      int r = lg * 4 + reg, c = wv * 16 + l15;
      float act = lsw((aA[reg] + aB[reg] * LINV) + ib1[c]);
      u16 h, l; split2(act, h, l);
      AH1(0,r,c) = h; AH1(1,r,c) = l;
    }
  }
  __syncthreads();
  if (wv < 4) { // L3 init: O=64, tile wv
    f32x4 aA = {0,0,0,0}, aB = {0,0,0,0};
#pragma unroll
    for (int ks = 0; ks < 4; ++ks) {
      f16x8 xh = *(const f16x8*)&AH1(0, l15, ks*32 + lg*8);
      f16x8 xl = *(const f16x8*)&AH1(1, l15, ks*32 + lg*8);
      int off = ((wv * 4 + ks) * 64 + lane) * 8;
      f16x8 bh = ldfrag(fiw2h + off), bl = ldfrag(fiw2l + off);
      aA = mmh(xh, bh, aA);
      aB = mmh(xh, bl, mmh(xl, bh, aB));
    }
#pragma unroll
    for (int reg = 0; reg < 4; ++reg) {
      int r = lg * 4 + reg, c = wv * 16 + l15;
      float x0 = (aA[reg] + aB[reg] * LINV) + ib2[c];
      ZV(r,c) = x0; ZH(r,c) = x0;
      u16 h, l; split2(x0, h, l);
      AX(0,r,c) = h; AX(1,r,c) = l;
    }
  }
  __syncthreads();

  const float rbv = rb[0];

// W2 tile compute: consumes buffer (WH,WL) for tile NT
#define L3_COMPUTE(WH, WL, NT)                                                  \
  {                                                                             \
    f32x4 aA = {0,0,0,0}, aB = {0,0,0,0};                                       \
    _Pragma("unroll")                                                           \
    for (int ks = 0; ks < 4; ++ks) {                                            \
      aA = mmh(WH[ks], bfh[ks], aA);                                            \
      aB = mmh(WH[ks], bfl[ks], mmh(WL[ks], bfh[ks], aB));                      \
    }                                                                           \
    float pw = 0.f, pv = 0.f;                                                   \
    _Pragma("unroll")                                                           \
    for (int reg = 0; reg < 4; ++reg) {                                         \
      int c = (NT) * 16 + lg * 4 + reg;                                         \
      float g = tanh_fast((aA[reg] + aB[reg] * LINV) + s_gb2[c]);               \
      pw += g * dw0v[reg];                                                      \
      pv += g * dw1v[reg];                                                      \
    }                                                                           \
    pw += __shfl_xor(pw, 16); pw += __shfl_xor(pw, 32);                         \
    pv += __shfl_xor(pv, 16); pv += __shfl_xor(pv, 32);                         \
    if (lane < 16) { SW(lane, (NT)) = pw; SV(lane, (NT)) = pv; }                \
  }

#define L3_PREFETCH(WH, WL, NT)                                                 \
  {                                                                             \
    _Pragma("unroll")                                                           \
    for (int ks = 0; ks < 4; ++ks) {                                            \
      int off = (((NT) * 4 + ks) * 64 + lane) * 8;                              \
      WH[ks] = ldfrag(fgw2h + off);                                             \
      WL[ks] = ldfrag(fgw2l + off);                                             \
    }                                                                           \
  }

  // ---------------- time loop ----------------
  for (int n = 0; n < T_STEPS; ++n) {
    if (n > 0) {
      // phase A: zhat_n = 2z - zhat + v ; z += 0.5 v ; stage x limbs
#pragma unroll
      for (int i = 0; i < 2; ++i) {
        int r = wv * 2 + i, h = lane;
        float z = ZV(r,h), zh = ZH(r,h), v = SV(r,h);
        float zhn = 2.f * z - zh + v;
        ZH(r,h) = zhn;
        u16 hh, ll; split2(zhn, hh, ll);
        AX(0,r,h) = hh; AX(1,r,h) = ll;
        ZV(r,h) = z + 0.5f * v;
      }
      if (n < T_STEPS - 1 && tid < 256) {
        float sdt = sqrtf(s_ts[n + 1] - s_ts[n]);
        int r = tid >> 4, nn = tid & 15;
        SDW(n & 1, r, nn) = dW[(n * B_TOT + R + r) * 16 + nn] * sdt;
      }
      __syncthreads();
    }
    const float tval = s_ts[n];
    { // L1: h0 = lsw(x@gw0[1:] + gb0 + t*gw0[0]), tile t = wv, gw0 streamed (L2-hit)
      f32x4 aA = {0,0,0,0}, aB = {0,0,0,0};
#pragma unroll
      for (int ks = 0; ks < 2; ++ks) {
        f16x8 xh = *(const f16x8*)&AX(0, l15, ks*32 + lg*8);
        f16x8 xl = *(const f16x8*)&AX(1, l15, ks*32 + lg*8);
        int off = ((wv * 2 + ks) * 64 + lane) * 8;
        f16x8 bh = ldfrag(fgw0h + off);
        f16x8 bl = ldfrag(fgw0l + off);
        aA = mmh(xh, bh, aA);
        aB = mmh(xh, bl, mmh(xl, bh, aB));
      }
#pragma unroll
      for (int reg = 0; reg < 4; ++reg) {
        int r = lg * 4 + reg, c = wv * 16 + l15;
        float act = lsw((aA[reg] + aB[reg] * LINV) + s_gb0[c] + tval * s_w0r0[c]);
        u16 h, l; split2(act, h, l);
        AH0(0,r,c) = h; AH0(1,r,c) = l;
      }
    }
    __syncthreads();
    f16x8 whA[4], wlA[4], whB[4], wlB[4];   // j-loop double buffer (fp16: 32 regs)
    { // L2: h1 = lsw(h0@gw1 + gb1), tile t = wv, gw1 limbs from LDS
      // issue j=0 W2 prefetch first: global-only, latency hides under L2 MFMAs
      L3_PREFETCH(whA, wlA, wv * 8 + jrot);
      f32x4 aA = {0,0,0,0}, aB = {0,0,0,0};
#pragma unroll
      for (int ks = 0; ks < 4; ++ks) {
        f16x8 xh = *(const f16x8*)&AH0(0, l15, ks*32 + lg*8);
        f16x8 xl = *(const f16x8*)&AH0(1, l15, ks*32 + lg*8);
        int off = ((wv * 4 + ks) * 64 + lane) * 8;
        f16x8 bh = *(const f16x8*)&s_w1h[off];
        f16x8 bl = *(const f16x8*)&s_w1l[off];
        aA = mmh(xh, bh, aA);
        aB = mmh(xh, bl, mmh(xl, bh, aB));
      }
#pragma unroll
      for (int reg = 0; reg < 4; ++reg) {
        int r = lg * 4 + reg, c = wv * 16 + l15;
        float act = lsw((aA[reg] + aB[reg] * LINV) + s_gb1[c]);
        u16 h, l; split2(act, h, l);
        AH1(0,r,c) = h; AH1(1,r,c) = l;
      }
    }
    __syncthreads();
    // L3 transposed (D' = W2^T h1^T): software-pipelined fp16 W2 stream
    float dw0v[4], dw1v[4];
#pragma unroll
    for (int reg = 0; reg < 4; ++reg) {
      dw0v[reg] = SDW((n - 1) & 1, l15, lg * 4 + reg);
      dw1v[reg] = SDW(n & 1,       l15, lg * 4 + reg);
    }
    f16x8 bfh[4], bfl[4];
#pragma unroll
    for (int ks = 0; ks < 4; ++ks) {
      bfh[ks] = *(const f16x8*)&AH1(0, l15, ks*32 + lg*8);
      bfl[ks] = *(const f16x8*)&AH1(1, l15, ks*32 + lg*8);
    }
#pragma unroll 1
    for (int j = 0; j < 8; j += 2) {
      const int ntA = wv * 8 + ((j + jrot) & 7);
      const int ntB = wv * 8 + ((j + 1 + jrot) & 7);
      L3_PREFETCH(whB, wlB, ntB);          // prefetch j+1 while computing j
      L3_COMPUTE(whA, wlA, ntA);
      if (j < 6) {
        const int ntA2 = wv * 8 + ((j + 2 + jrot) & 7);
        L3_PREFETCH(whA, wlA, ntA2);       // prefetch j+2 while computing j+1
      }
      L3_COMPUTE(whB, wlB, ntB);
    }
    __syncthreads();
    // phase D: z_n = z + 0.5 w ; emit (ts, z.rw + rb)
#pragma unroll
    for (int i = 0; i < 2; ++i) {
      int r = wv * 2 + i, h = lane;
      float z = ZV(r,h);
      if (n > 0) { z += 0.5f * SW(r,h); ZV(r,h) = z; }
      float p = z * s_rw[h];
#pragma unroll
      for (int off = 32; off >= 1; off >>= 1) p += __shfl_xor(p, off);
      if (lane == 0) {
        int o = ((R + r) * T_STEPS + n) * 2;
        out[o] = tval; out[o + 1] = p + rbv;
      }
    }
  }
}

extern "C" void kernel_launch(void* const* d_in, const int* in_sizes, int n_in,
                              void* d_out, int out_size, void* d_ws, size_t ws_size,
                              hipStream_t stream) {
  (void)in_sizes; (void)n_in; (void)out_size; (void)ws_size;
  const float* ts = (const float*)d_in[0];
  const float* init_noise = (const float*)d_in[2];
  const float* dW  = (const float*)d_in[3];
  const float* iw0 = (const float*)d_in[4];
  const float* ib0 = (const float*)d_in[5];
  const float* iw1 = (const float*)d_in[6];
  const float* ib1 = (const float*)d_in[7];
  const float* iw2 = (const float*)d_in[8];
  const float* ib2 = (const float*)d_in[9];
  const float* gw0 = (const float*)d_in[10];
  const float* gb0 = (const float*)d_in[11];
  const float* gw1 = (const float*)d_in[12];
  const float* gb1 = (const float*)d_in[13];
  const float* gw2 = (const float*)d_in[14];
  const float* gb2 = (const float*)d_in[15];
  const float* rw  = (const float*)d_in[16];
  const float* rb  = (const float*)d_in[17];

  u16* ws = (u16*)d_ws;
  const int LO = 188416;  // elems per limb block
  u16* fiw0h = ws + 0;      u16* fiw0l = ws + LO + 0;
  u16* fiw1h = ws + 8192;   u16* fiw1l = ws + LO + 8192;
  u16* fiw2h = ws + 24576;  u16* fiw2l = ws + LO + 24576;
  u16* fgw0h = ws + 32768;  u16* fgw0l = ws + LO + 32768;
  u16* fgw1h = ws + 40960;  u16* fgw1l = ws + LO + 40960;
  u16* fgw2h = ws + 57344;  u16* fgw2l = ws + LO + 57344;

  frag_w2<<<32,  256, 0, stream>>>(iw0, 2, 128, 0, fiw0h, fiw0l, 8192);
  frag_w2<<<64,  256, 0, stream>>>(iw1, 4, 128, 0, fiw1h, fiw1l, 16384);
  frag_w2<<<32,  256, 0, stream>>>(iw2, 4, 64,  0, fiw2h, fiw2l, 8192);
  frag_w2<<<32,  256, 0, stream>>>(gw0, 2, 128, 1, fgw0h, fgw0l, 8192);
  frag_w2<<<64,  256, 0, stream>>>(gw1, 4, 128, 0, fgw1h, fgw1l, 16384);
  frag_w2<<<512, 256, 0, stream>>>(gw2, 4, 1024, 0, fgw2h, fgw2l, 131072);

  hipFuncSetAttribute((const void*)sde_gen,
                      hipFuncAttributeMaxDynamicSharedMemorySize, SMEM_BYTES);
  sde_gen<<<256, 512, SMEM_BYTES, stream>>>(
      ts, init_noise, dW, ib0, ib1, ib2, gw0, gb0, gb1, gb2, rw, rb,
      fiw0h, fiw0l, fiw1h, fiw1l, fiw2h, fiw2l,
      fgw0h, fgw0l, fgw1h, fgw1l, fgw2h, fgw2l,
      (float*)d_out);
}

// Round 13
// 875.718 us; speedup vs baseline: 1.7844x; 1.1152x over previous
//
#include <hip/hip_runtime.h>

typedef unsigned short u16;
typedef _Float16 f16;
typedef __attribute__((ext_vector_type(8))) _Float16 f16x8;
typedef __attribute__((ext_vector_type(4))) float f32x4;

#define B_TOT 4096
#define T_STEPS 128
#define SMEM_BYTES 113024
#define LSCALE 2048.f
#define LINV   4.8828125e-4f   // 1/2048, exact

__device__ __forceinline__ u16 f2h(float x) {
  union { f16 h; u16 u; } v; v.h = (f16)x; return v.u;
}
__device__ __forceinline__ float h2f(u16 b) {
  union { u16 u; f16 h; } v; v.u = b; return (float)v.h;
}
// 2-limb fp16 split with scaled low limb: x ~= h + l/2048 to ~2^-22 rel.
__device__ __forceinline__ void split2(float x, u16& h, u16& l) {
  h = f2h(x);
  float r = x - h2f(h);
  l = f2h(r * LSCALE);
}
__device__ __forceinline__ float fastrcp(float x) {   // v_rcp_f32, ~1 ulp
  return __builtin_amdgcn_rcpf(x);
}
__device__ __forceinline__ float lsw(float u) {       // 0.909 * u * sigmoid(u)
  return 0.909f * u * fastrcp(1.f + __expf(-u));
}
__device__ __forceinline__ float tanh_fast(float u) {
  return 1.f - 2.f * fastrcp(1.f + __expf(2.f * u));
}
__device__ __forceinline__ f32x4 mmh(f16x8 a, f16x8 b, f32x4 c) {
  return __builtin_amdgcn_mfma_f32_16x16x32_f16(a, b, c, 0, 0, 0);
}
__device__ __forceinline__ f16x8 ldfrag(const u16* p) { return *(const f16x8*)p; }

// Pre-fragment W[K][O] (row-major, ld ldW) into 2 fp16 limbs in MFMA fragment order:
// dst[((nt*KS+ks)*64+lane)*8+e] = W[rowOff + ks*32 + (lane>>4)*8 + e][nt*16 + (lane&15)]
__global__ void frag_w2(const float* __restrict__ W, int KS, int ldW, int rowOff,
                        u16* __restrict__ dh, u16* __restrict__ dl, int nElems) {
  int i = blockIdx.x * blockDim.x + threadIdx.x;
  if (i >= nElems) return;
  int e = i & 7, lane = (i >> 3) & 63, rest = i >> 9;
  int ks = rest % KS, nt = rest / KS;
  int row = rowOff + ks * 32 + ((lane >> 4) * 8) + e;
  int col = nt * 16 + (lane & 15);
  float w = W[row * ldW + col];
  u16 h, l; split2(w, h, l);
  dh[i] = h; dl[i] = l;
}

__global__ __launch_bounds__(512, 1) void sde_gen(
    const float* __restrict__ ts, const float* __restrict__ init_noise,
    const float* __restrict__ dW,
    const float* __restrict__ ib0, const float* __restrict__ ib1, const float* __restrict__ ib2,
    const float* __restrict__ gw0, const float* __restrict__ gb0,
    const float* __restrict__ gb1, const float* __restrict__ gb2,
    const float* __restrict__ rw, const float* __restrict__ rb,
    const u16* __restrict__ fiw0h, const u16* __restrict__ fiw0l,
    const u16* __restrict__ fiw1h, const u16* __restrict__ fiw1l,
    const u16* __restrict__ fiw2h, const u16* __restrict__ fiw2l,
    const u16* __restrict__ fgw0h, const u16* __restrict__ fgw0l,
    const u16* __restrict__ fgw1h, const u16* __restrict__ fgw1l,
    const u16* __restrict__ fgw2h, const u16* __restrict__ fgw2l,
    float* __restrict__ out) {
  extern __shared__ char smem[];
  u16*   s_w1h  = (u16*)(smem);            // [16384] gw1 hi frags
  u16*   s_w1l  = (u16*)(smem + 32768);    // [16384] gw1 lo frags
  u16*   s_ax   = (u16*)(smem + 65536);    // [2][16][72]
  u16*   s_ah0  = (u16*)(smem + 70144);    // [2][16][136]
  u16*   s_ah1  = (u16*)(smem + 78848);    // [2][16][136]
  float* s_z    = (float*)(smem + 87552);  // [16][64]
  float* s_zh   = (float*)(smem + 91648);  // [16][64]
  float* s_v    = (float*)(smem + 95744);  // [16][68]
  float* s_w    = (float*)(smem + 100096); // [16][68]
  float* s_dw   = (float*)(smem + 104448); // [2][16][17]
  float* s_ts   = (float*)(smem + 106624); // [128]
  float* s_gb0  = (float*)(smem + 107136);
  float* s_w0r0 = (float*)(smem + 107648);
  float* s_gb1  = (float*)(smem + 108160);
  float* s_gb2  = (float*)(smem + 108672); // [1024]
  float* s_rw   = (float*)(smem + 112768); // [64]
#define AX(L,r,c)   s_ax [((L)*16+(r))*72 +(c)]
#define AH0(L,r,c)  s_ah0[((L)*16+(r))*136+(c)]
#define AH1(L,r,c)  s_ah1[((L)*16+(r))*136+(c)]
#define ZV(r,c)  s_z [(r)*64+(c)]
#define ZH(r,c)  s_zh[(r)*64+(c)]
#define SV(r,c)  s_v [(r)*68+(c)]
#define SW(r,c)  s_w [(r)*68+(c)]
#define SDW(b,r,c) s_dw[((b)*16+(r))*17+(c)]

  const int tid = threadIdx.x;
  const int wv = tid >> 6;        // 0..7
  const int lane = tid & 63;
  const int l15 = lane & 15, lg = lane >> 4;
  const int R = blockIdx.x * 16;
  const int jrot = blockIdx.x & 7;   // de-correlate W2 L2-line access across blocks

  // ---- one-time loads ----
  for (int i = tid; i < 128; i += 512) {
    s_ts[i] = ts[i]; s_gb0[i] = gb0[i]; s_gb1[i] = gb1[i]; s_w0r0[i] = gw0[i];
  }
  for (int i = tid; i < 1024; i += 512) s_gb2[i] = gb2[i];
  if (tid < 64) s_rw[tid] = rw[tid];
  for (int i = tid; i < 2048; i += 512) {   // gw1 limb frags -> LDS (64 KB)
    ((f16x8*)s_w1h)[i] = ((const f16x8*)fgw1h)[i];
    ((f16x8*)s_w1l)[i] = ((const f16x8*)fgw1l)[i];
  }
  for (int i = tid; i < 16 * 64; i += 512) {
    int r = i >> 6, k = i & 63;
    float x = init_noise[(R + r) * 64 + k];
    u16 h, l; split2(x, h, l);
    AX(0,r,k) = h; AX(1,r,k) = l;
  }
  if (tid < 256) { // dWs[0]; zero dWs buf 1
    float sdt = sqrtf(ts[1] - ts[0]);
    int r = tid >> 4, nn = tid & 15;
    SDW(0, r, nn) = dW[(0 * B_TOT + R + r) * 16 + nn] * sdt;
    SDW(1, r, nn) = 0.f;
  }
  __syncthreads();

  // ---------------- initial MLP (fp16x3-product) ----------------
  { // L1, K=64, tile t = wv (8 tiles)
    f32x4 aA = {0,0,0,0}, aB = {0,0,0,0};
#pragma unroll
    for (int ks = 0; ks < 2; ++ks) {
      f16x8 xh = *(const f16x8*)&AX(0, l15, ks*32 + lg*8);
      f16x8 xl = *(const f16x8*)&AX(1, l15, ks*32 + lg*8);
      int off = ((wv * 2 + ks) * 64 + lane) * 8;
      f16x8 bh = ldfrag(fiw0h + off), bl = ldfrag(fiw0l + off);
      aA = mmh(xh, bh, aA);
      aB = mmh(xh, bl, mmh(xl, bh, aB));
    }
#pragma unroll
    for (int reg = 0; reg < 4; ++reg) {
      int r = lg * 4 + reg, c = wv * 16 + l15;
      float act = lsw((aA[reg] + aB[reg] * LINV) + ib0[c]);
      u16 h, l; split2(act, h, l);
      AH0(0,r,c) = h; AH0(1,r,c) = l;
    }
  }
  __syncthreads();
  { // L2, K=128, tile t = wv
    f32x4 aA = {0,0,0,0}, aB = {0,0,0,0};
#pragma unroll
    for (int ks = 0; ks < 4; ++ks) {
      f16x8 xh = *(const f16x8*)&AH0(0, l15, ks*32 + lg*8);
      f16x8 xl = *(const f16x8*)&AH0(1, l15, ks*32 + lg*8);
      int off = ((wv * 4 + ks) * 64 + lane) * 8;
      f16x8 bh = ldfrag(fiw1h + off), bl = ldfrag(fiw1l + off);
      aA = mmh(xh, bh, aA);
      aB = mmh(xh, bl, mmh(xl, bh, aB));
    }
#pragma unroll
    for (int reg = 0; reg < 4; ++reg) {
      int r = lg * 4 + reg, c = wv * 16 + l15;
      float act = lsw((aA[reg] + aB[reg] * LINV) + ib1[c]);
      u16 h, l; split2(act, h, l);
      AH1(0,r,c) = h; AH1(1,r,c) = l;
    }
  }
  __syncthreads();
  if (wv < 4) { // L3 init: O=64, tile wv
    f32x4 aA = {0,0,0,0}, aB = {0,0,0,0};
#pragma unroll
    for (int ks = 0; ks < 4; ++ks) {
      f16x8 xh = *(const f16x8*)&AH1(0, l15, ks*32 + lg*8);
      f16x8 xl = *(const f16x8*)&AH1(1, l15, ks*32 + lg*8);
      int off = ((wv * 4 + ks) * 64 + lane) * 8;
      f16x8 bh = ldfrag(fiw2h + off), bl = ldfrag(fiw2l + off);
      aA = mmh(xh, bh, aA);
      aB = mmh(xh, bl, mmh(xl, bh, aB));
    }
#pragma unroll
    for (int reg = 0; reg < 4; ++reg) {
      int r = lg * 4 + reg, c = wv * 16 + l15;
      float x0 = (aA[reg] + aB[reg] * LINV) + ib2[c];
      ZV(r,c) = x0; ZH(r,c) = x0;
      u16 h, l; split2(x0, h, l);
      AX(0,r,c) = h; AX(1,r,c) = l;
    }
  }
  __syncthreads();

  const float rbv = rb[0];

// W2 tile compute: consumes buffer (WH,WL) for tile NT
#define L3_COMPUTE(WH, WL, NT)                                                  \
  {                                                                             \
    f32x4 aA = {0,0,0,0}, aB = {0,0,0,0};                                       \
    _Pragma("unroll")                                                           \
    for (int ks = 0; ks < 4; ++ks) {                                            \
      aA = mmh(WH[ks], bfh[ks], aA);                                            \
      aB = mmh(WH[ks], bfl[ks], mmh(WL[ks], bfh[ks], aB));                      \
    }                                                                           \
    float pw = 0.f, pv = 0.f;                                                   \
    _Pragma("unroll")                                                           \
    for (int reg = 0; reg < 4; ++reg) {                                         \
      int c = (NT) * 16 + lg * 4 + reg;                                         \
      float g = tanh_fast((aA[reg] + aB[reg] * LINV) + s_gb2[c]);               \
      pw += g * dw0v[reg];                                                      \
      pv += g * dw1v[reg];                                                      \
    }                                                                           \
    pw += __shfl_xor(pw, 16); pw += __shfl_xor(pw, 32);                         \
    pv += __shfl_xor(pv, 16); pv += __shfl_xor(pv, 32);                         \
    if (lane < 16) { SW(lane, (NT)) = pw; SV(lane, (NT)) = pv; }                \
  }

#define L3_PREFETCH(WH, WL, NT)                                                 \
  {                                                                             \
    _Pragma("unroll")                                                           \
    for (int ks = 0; ks < 4; ++ks) {                                            \
      int off = (((NT) * 4 + ks) * 64 + lane) * 8;                              \
      WH[ks] = ldfrag(fgw2h + off);                                             \
      WL[ks] = ldfrag(fgw2l + off);                                             \
    }                                                                           \
  }

  // ---------------- time loop ----------------
  for (int n = 0; n < T_STEPS; ++n) {
    if (n > 0) {
      // phase A: zhat_n = 2z - zhat + v ; z += 0.5 v ; stage x limbs
#pragma unroll
      for (int i = 0; i < 2; ++i) {
        int r = wv * 2 + i, h = lane;
        float z = ZV(r,h), zh = ZH(r,h), v = SV(r,h);
        float zhn = 2.f * z - zh + v;
        ZH(r,h) = zhn;
        u16 hh, ll; split2(zhn, hh, ll);
        AX(0,r,h) = hh; AX(1,r,h) = ll;
        ZV(r,h) = z + 0.5f * v;
      }
      if (n < T_STEPS - 1 && tid < 256) {
        float sdt = sqrtf(s_ts[n + 1] - s_ts[n]);
        int r = tid >> 4, nn = tid & 15;
        SDW(n & 1, r, nn) = dW[(n * B_TOT + R + r) * 16 + nn] * sdt;
      }
      __syncthreads();
    }
    const float tval = s_ts[n];
    { // L1: h0 = lsw(x@gw0[1:] + gb0 + t*gw0[0]), tile t = wv, gw0 streamed (L2-hit)
      f32x4 aA = {0,0,0,0}, aB = {0,0,0,0};
#pragma unroll
      for (int ks = 0; ks < 2; ++ks) {
        f16x8 xh = *(const f16x8*)&AX(0, l15, ks*32 + lg*8);
        f16x8 xl = *(const f16x8*)&AX(1, l15, ks*32 + lg*8);
        int off = ((wv * 2 + ks) * 64 + lane) * 8;
        f16x8 bh = ldfrag(fgw0h + off);
        f16x8 bl = ldfrag(fgw0l + off);
        aA = mmh(xh, bh, aA);
        aB = mmh(xh, bl, mmh(xl, bh, aB));
      }
#pragma unroll
      for (int reg = 0; reg < 4; ++reg) {
        int r = lg * 4 + reg, c = wv * 16 + l15;
        float act = lsw((aA[reg] + aB[reg] * LINV) + s_gb0[c] + tval * s_w0r0[c]);
        u16 h, l; split2(act, h, l);
        AH0(0,r,c) = h; AH0(1,r,c) = l;
      }
    }
    __syncthreads();
    f16x8 whA[4], wlA[4], whB[4], wlB[4];   // j-loop double buffer (fp16: 32 regs)
    { // L2: h1 = lsw(h0@gw1 + gb1), tile t = wv, gw1 limbs from LDS
      // issue j=0 W2 prefetch first: global-only, latency hides under L2 MFMAs
      L3_PREFETCH(whA, wlA, wv * 8 + jrot);
      f32x4 aA = {0,0,0,0}, aB = {0,0,0,0};
#pragma unroll
      for (int ks = 0; ks < 4; ++ks) {
        f16x8 xh = *(const f16x8*)&AH0(0, l15, ks*32 + lg*8);
        f16x8 xl = *(const f16x8*)&AH0(1, l15, ks*32 + lg*8);
        int off = ((wv * 4 + ks) * 64 + lane) * 8;
        f16x8 bh = *(const f16x8*)&s_w1h[off];
        f16x8 bl = *(const f16x8*)&s_w1l[off];
        aA = mmh(xh, bh, aA);
        aB = mmh(xh, bl, mmh(xl, bh, aB));
      }
#pragma unroll
      for (int reg = 0; reg < 4; ++reg) {
        int r = lg * 4 + reg, c = wv * 16 + l15;
        float act = lsw((aA[reg] + aB[reg] * LINV) + s_gb1[c]);
        u16 h, l; split2(act, h, l);
        AH1(0,r,c) = h; AH1(1,r,c) = l;
      }
    }
    __syncthreads();
    // L3 transposed (D' = W2^T h1^T): software-pipelined fp16 W2 stream
    float dw0v[4], dw1v[4];
#pragma unroll
    for (int reg = 0; reg < 4; ++reg) {
      dw0v[reg] = SDW((n - 1) & 1, l15, lg * 4 + reg);
      dw1v[reg] = SDW(n & 1,       l15, lg * 4 + reg);
    }
    f16x8 bfh[4], bfl[4];
#pragma unroll
    for (int ks = 0; ks < 4; ++ks) {
      bfh[ks] = *(const f16x8*)&AH1(0, l15, ks*32 + lg*8);
      bfl[ks] = *(const f16x8*)&AH1(1, l15, ks*32 + lg*8);
    }
#pragma unroll 1
    for (int j = 0; j < 8; j += 2) {
      const int ntA = wv * 8 + ((j + jrot) & 7);
      const int ntB = wv * 8 + ((j + 1 + jrot) & 7);
      L3_PREFETCH(whB, wlB, ntB);          // prefetch j+1 while computing j
      L3_COMPUTE(whA, wlA, ntA);
      if (j < 6) {
        const int ntA2 = wv * 8 + ((j + 2 + jrot) & 7);
        L3_PREFETCH(whA, wlA, ntA2);       // prefetch j+2 while computing j+1
      }
      L3_COMPUTE(whB, wlB, ntB);
    }
    __syncthreads();
    // phase D: z_n = z + 0.5 w ; emit (ts, z.rw + rb)
#pragma unroll
    for (int i = 0; i < 2; ++i) {
      int r = wv * 2 + i, h = lane;
      float z = ZV(r,h);
      if (n > 0) { z += 0.5f * SW(r,h); ZV(r,h) = z; }
      float p = z * s_rw[h];
#pragma unroll
      for (int off = 32; off >= 1; off >>= 1) p += __shfl_xor(p, off);
      if (lane == 0) {
        int o = ((R + r) * T_STEPS + n) * 2;
        out[o] = tval; out[o + 1] = p + rbv;
      }
    }
  }
}

extern "C" void kernel_launch(void* const* d_in, const int* in_sizes, int n_in,
                              void* d_out, int out_size, void* d_ws, size_t ws_size,
                              hipStream_t stream) {
  (void)in_sizes; (void)n_in; (void)out_size; (void)ws_size;
  const float* ts = (const float*)d_in[0];
  const float* init_noise = (const float*)d_in[2];
  const float* dW  = (const float*)d_in[3];
  const float* iw0 = (const float*)d_in[4];
  const float* ib0 = (const float*)d_in[5];
  const float* iw1 = (const float*)d_in[6];
  const float* ib1 = (const float*)d_in[7];
  const float* iw2 = (const float*)d_in[8];
  const float* ib2 = (const float*)d_in[9];
  const float* gw0 = (const float*)d_in[10];
  const float* gb0 = (const float*)d_in[11];
  const float* gw1 = (const float*)d_in[12];
  const float* gb1 = (const float*)d_in[13];
  const float* gw2 = (const float*)d_in[14];
  const float* gb2 = (const float*)d_in[15];
  const float* rw  = (const float*)d_in[16];
  const float* rb  = (const float*)d_in[17];

  u16* ws = (u16*)d_ws;
  const int LO = 188416;  // elems per limb block
  u16* fiw0h = ws + 0;      u16* fiw0l = ws + LO + 0;
  u16* fiw1h = ws + 8192;   u16* fiw1l = ws + LO + 8192;
  u16* fiw2h = ws + 24576;  u16* fiw2l = ws + LO + 24576;
  u16* fgw0h = ws + 32768;  u16* fgw0l = ws + LO + 32768;
  u16* fgw1h = ws + 40960;  u16* fgw1l = ws + LO + 40960;
  u16* fgw2h = ws + 57344;  u16* fgw2l = ws + LO + 57344;

  frag_w2<<<32,  256, 0, stream>>>(iw0, 2, 128, 0, fiw0h, fiw0l, 8192);
  frag_w2<<<64,  256, 0, stream>>>(iw1, 4, 128, 0, fiw1h, fiw1l, 16384);
  frag_w2<<<32,  256, 0, stream>>>(iw2, 4, 64,  0, fiw2h, fiw2l, 8192);
  frag_w2<<<32,  256, 0, stream>>>(gw0, 2, 128, 1, fgw0h, fgw0l, 8192);
  frag_w2<<<64,  256, 0, stream>>>(gw1, 4, 128, 0, fgw1h, fgw1l, 16384);
  frag_w2<<<512, 256, 0, stream>>>(gw2, 4, 1024, 0, fgw2h, fgw2l, 131072);

  hipFuncSetAttribute((const void*)sde_gen,
                      hipFuncAttributeMaxDynamicSharedMemorySize, SMEM_BYTES);
  sde_gen<<<256, 512, SMEM_BYTES, stream>>>(
      ts, init_noise, dW, ib0, ib1, ib2, gw0, gb0, gb1, gb2, rw, rb,
      fiw0h, fiw0l, fiw1h, fiw1l, fiw2h, fiw2l,
      fgw0h, fgw0l, fgw1h, fgw1l, fgw2h, fgw2l,
      (float*)d_out);
}